// Round 1
// baseline (293.158 us; speedup 1.0000x reference)
//
#include <hip/hip_runtime.h>
#include <math.h>

#define B_   64
#define C_   103
#define HW_  65536
#define R_   3
#define E_   3
#define HID_ 64

// ---------------- Pool: pooled[b*C+c] = mean(x[b][c][:][:]) ----------------
// One block per (b,c) row; 65536 contiguous floats per row.
__global__ __launch_bounds__(256) void pool_kernel(const float* __restrict__ x,
                                                   float* __restrict__ pooled) {
    const int row = blockIdx.x;                 // b*C + c
    const float4* __restrict__ p =
        reinterpret_cast<const float4*>(x + (size_t)row * HW_);
    const int t = threadIdx.x;

    float s = 0.0f;
    #pragma unroll 4
    for (int i = 0; i < 64; ++i) {              // 64 * 256 float4 = 16384 = HW/4
        float4 v = p[t + i * 256];
        s += (v.x + v.y) + (v.z + v.w);
    }
    // 64-lane wave butterfly reduce
    #pragma unroll
    for (int off = 32; off > 0; off >>= 1) s += __shfl_xor(s, off, 64);

    __shared__ float ws[4];
    const int lane = t & 63, wid = t >> 6;
    if (lane == 0) ws[wid] = s;
    __syncthreads();
    if (t == 0) {
        float tot = (ws[0] + ws[1]) + (ws[2] + ws[3]);
        pooled[row] = tot * (1.0f / (float)HW_);
    }
}

// ---------------- Gate: MLP + top2 + softmax, one block per batch ----------------
__global__ __launch_bounds__(192) void gate_kernel(const float* __restrict__ pooled,
                                                   const float* __restrict__ W1,
                                                   const float* __restrict__ b1,
                                                   const float* __restrict__ W2,
                                                   const float* __restrict__ b2,
                                                   float* __restrict__ out) {
    const int b = blockIdx.x;
    const int t = threadIdx.x;

    __shared__ float sp[C_];          // pooled row
    __shared__ float sh[R_ * HID_];   // hidden activations
    __shared__ float sl[R_ * E_];     // logits

    if (t < C_) sp[t] = pooled[b * C_ + t];
    __syncthreads();

    // h[r][hid] = relu(dot(pooled, W1[r][hid][:]) + b1[r][hid])   (192 threads)
    {
        const float* __restrict__ w = W1 + (size_t)t * C_;   // t = r*HID + hid
        float acc = b1[t];
        #pragma unroll 
        for (int c = 0; c < C_; ++c) acc = fmaf(sp[c], w[c], acc);
        sh[t] = fmaxf(acc, 0.0f);
    }
    __syncthreads();

    // logits[r][e] = dot(h[r], W2[r][e][:]) + b2[r][e]   (9 threads)
    if (t < R_ * E_) {
        const int r = t / E_;
        const float* __restrict__ w = W2 + (size_t)t * HID_;
        float acc = b2[t];
        #pragma unroll
        for (int k = 0; k < HID_; ++k) acc = fmaf(sh[r * HID_ + k], w[k], acc);
        sl[t] = acc;
        // gate_logits output: offset 768, layout [B][R][E]
        out[768 + b * (R_ * E_) + t] = acc;
    }
    __syncthreads();

    // top-2 (stable, lowest index wins ties) + softmax over the 2 kept logits
    if (t < R_) {
        const float g0 = sl[t * E_ + 0];
        const float g1 = sl[t * E_ + 1];
        const float g2 = sl[t * E_ + 2];
        float g[3] = {g0, g1, g2};

        int i0 = 0;
        if (g[1] > g[i0]) i0 = 1;
        if (g[2] > g[i0]) i0 = 2;
        int i1 = -1;
        #pragma unroll
        for (int i = 0; i < 3; ++i) {
            if (i == i0) continue;
            if (i1 < 0 || g[i] > g[i1]) i1 = i;
        }
        const float v0 = g[i0], v1 = g[i1];
        const float e1 = expf(v1 - v0);          // v0 is the max
        const float inv = 1.0f / (1.0f + e1);

        const int base = b * (R_ * 2) + t * 2;
        // top_k_indices (as float), offset 0, layout [B][R][2]
        out[base + 0] = (float)i0;
        out[base + 1] = (float)i1;
        // top_k_scores, offset 384, layout [B][R][2]
        out[384 + base + 0] = inv;
        out[384 + base + 1] = e1 * inv;
    }
}

extern "C" void kernel_launch(void* const* d_in, const int* in_sizes, int n_in,
                              void* d_out, int out_size, void* d_ws, size_t ws_size,
                              hipStream_t stream) {
    const float* x  = (const float*)d_in[0];   // [64,103,256,256]
    const float* W1 = (const float*)d_in[1];   // [3,64,103]
    const float* b1 = (const float*)d_in[2];   // [3,64]
    const float* W2 = (const float*)d_in[3];   // [3,3,64]
    const float* b2 = (const float*)d_in[4];   // [3,3]
    float* out      = (float*)d_out;           // 1344 floats: idx(384) | scores(384) | logits(576)
    float* pooled   = (float*)d_ws;            // B*C = 6592 floats scratch

    pool_kernel<<<B_ * C_, 256, 0, stream>>>(x, pooled);
    gate_kernel<<<B_, 192, 0, stream>>>(pooled, W1, b1, W2, b2, out);
}

// Round 3
// 253.524 us; speedup vs baseline: 1.1563x; 1.1563x over previous
//
#include <hip/hip_runtime.h>
#include <math.h>

#define B_   64
#define C_   103
#define HW_  65536
#define R_   3
#define E_   3
#define HID_ 64

// Native clang vector type — __builtin_nontemporal_load requires it
// (HIP_vector_type float4 is a struct and is rejected).
typedef float f4_t __attribute__((ext_vector_type(4)));

// ---------------- Pool: pooled[b*C+c] = mean(x[b][c][:][:]) ----------------
// One block per (b,c) row; 65536 contiguous floats per row.
// Non-temporal loads (streaming data, zero reuse) + deeper unroll for MLP.
__global__ __launch_bounds__(256) void pool_kernel(const float* __restrict__ x,
                                                   float* __restrict__ pooled) {
    const int row = blockIdx.x;                 // b*C + c
    const f4_t* __restrict__ p =
        reinterpret_cast<const f4_t*>(x + (size_t)row * HW_);
    const int t = threadIdx.x;

    float s = 0.0f;
    #pragma unroll 8
    for (int i = 0; i < 64; ++i) {              // 64 * 256 float4 = 16384 = HW/4
        f4_t v = __builtin_nontemporal_load(&p[t + i * 256]);
        s += (v.x + v.y) + (v.z + v.w);
    }
    // 64-lane wave butterfly reduce
    #pragma unroll
    for (int off = 32; off > 0; off >>= 1) s += __shfl_xor(s, off, 64);

    __shared__ float ws[4];
    const int lane = t & 63, wid = t >> 6;
    if (lane == 0) ws[wid] = s;
    __syncthreads();
    if (t == 0) {
        float tot = (ws[0] + ws[1]) + (ws[2] + ws[3]);
        pooled[row] = tot * (1.0f / (float)HW_);
    }
}

// ---------------- Gate: MLP + top2 + softmax, one block per batch ----------------
__global__ __launch_bounds__(192) void gate_kernel(const float* __restrict__ pooled,
                                                   const float* __restrict__ W1,
                                                   const float* __restrict__ b1,
                                                   const float* __restrict__ W2,
                                                   const float* __restrict__ b2,
                                                   float* __restrict__ out) {
    const int b = blockIdx.x;
    const int t = threadIdx.x;

    __shared__ float sp[C_];          // pooled row
    __shared__ float sh[R_ * HID_];   // hidden activations
    __shared__ float sl[R_ * E_];     // logits

    if (t < C_) sp[t] = pooled[b * C_ + t];
    __syncthreads();

    // h[r][hid] = relu(dot(pooled, W1[r][hid][:]) + b1[r][hid])   (192 threads)
    {
        const float* __restrict__ w = W1 + (size_t)t * C_;   // t = r*HID + hid
        float acc = b1[t];
        #pragma unroll
        for (int c = 0; c < C_; ++c) acc = fmaf(sp[c], w[c], acc);
        sh[t] = fmaxf(acc, 0.0f);
    }
    __syncthreads();

    // logits[r][e] = dot(h[r], W2[r][e][:]) + b2[r][e]   (9 threads)
    if (t < R_ * E_) {
        const int r = t / E_;
        const float* __restrict__ w = W2 + (size_t)t * HID_;
        float acc = b2[t];
        #pragma unroll
        for (int k = 0; k < HID_; ++k) acc = fmaf(sh[r * HID_ + k], w[k], acc);
        sl[t] = acc;
        // gate_logits output: offset 768, layout [B][R][E]
        out[768 + b * (R_ * E_) + t] = acc;
    }
    __syncthreads();

    // top-2 (stable, lowest index wins ties) + softmax over the 2 kept logits
    if (t < R_) {
        const float g0 = sl[t * E_ + 0];
        const float g1 = sl[t * E_ + 1];
        const float g2 = sl[t * E_ + 2];
        float g[3] = {g0, g1, g2};

        int i0 = 0;
        if (g[1] > g[i0]) i0 = 1;
        if (g[2] > g[i0]) i0 = 2;
        int i1 = -1;
        #pragma unroll
        for (int i = 0; i < 3; ++i) {
            if (i == i0) continue;
            if (i1 < 0 || g[i] > g[i1]) i1 = i;
        }
        const float v0 = g[i0], v1 = g[i1];
        const float e1 = expf(v1 - v0);          // v0 is the max
        const float inv = 1.0f / (1.0f + e1);

        const int base = b * (R_ * 2) + t * 2;
        // top_k_indices (as float), offset 0, layout [B][R][2]
        out[base + 0] = (float)i0;
        out[base + 1] = (float)i1;
        // top_k_scores, offset 384, layout [B][R][2]
        out[384 + base + 0] = inv;
        out[384 + base + 1] = e1 * inv;
    }
}

extern "C" void kernel_launch(void* const* d_in, const int* in_sizes, int n_in,
                              void* d_out, int out_size, void* d_ws, size_t ws_size,
                              hipStream_t stream) {
    const float* x  = (const float*)d_in[0];   // [64,103,256,256]
    const float* W1 = (const float*)d_in[1];   // [3,64,103]
    const float* b1 = (const float*)d_in[2];   // [3,64]
    const float* W2 = (const float*)d_in[3];   // [3,3,64]
    const float* b2 = (const float*)d_in[4];   // [3,3]
    float* out      = (float*)d_out;           // 1344 floats: idx(384) | scores(384) | logits(576)
    float* pooled   = (float*)d_ws;            // B*C = 6592 floats scratch

    pool_kernel<<<B_ * C_, 256, 0, stream>>>(x, pooled);
    gate_kernel<<<B_, 192, 0, stream>>>(pooled, W1, b1, W2, b2, out);
}